// Round 3
// baseline (94.025 us; speedup 1.0000x reference)
//
#include <hip/hip_runtime.h>

#define LAMBDA_NOOBJ 0.5f
#define LAMBDA_COORD 5.0f

// Copy-µbench-shaped streaming kernel. Lane-adjacent float4 loads (1KB per
// wave-instruction, perfectly coalesced), no LDS staging. The 5-float cell
// structure is handled in-register: phase r = (chunk + 4*lane) mod 5 is
// loop-invariant (nwaves % 5 == 0), and the cross-cell conf value needed for
// coord terms comes from one __shfl_up per iteration.
__global__ __launch_bounds__(256) void yolo_loss_kernel(
    const float4* __restrict__ pred4,
    const float4* __restrict__ targ4,
    const float* __restrict__ pred,
    const float* __restrict__ targ,
    float* __restrict__ out,   // out[1]=box, out[2]=obj, out[3]=noobj
    long long nchunks,         // number of 256-element chunks
    long long nelem,           // total elements per input
    int nwaves) {
  const int lane = threadIdx.x & 63;
  const long long g = (long long)((blockIdx.x * blockDim.x + threadIdx.x) >> 6);

  // Element e = chunk*256 + 4*lane + c; chunk ≡ g (mod 5) since stride
  // nwaves ≡ 0 (mod 5) and 256 ≡ 1 (mod 5).
  const int r = (int)((g + 4LL * lane) % 5);   // phase of this lane's first elem
  const int cstar = (5 - r) % 5;    // component index holding conf (4 => none)
  const int r_nxt = (r + 4) % 5;    // next lane's phase
  const int prov_idx = (4 - r_nxt) & 3;  // which of my t[] the next lane needs

  float box = 0.f, obj = 0.f, noobj = 0.f;

#pragma unroll 2
  for (long long chunk = g; chunk < nchunks; chunk += nwaves) {
    const long long b4 = chunk * 64 + lane;  // float4 index
    float4 pq = pred4[b4];
    float4 tq = targ4[b4];
    float p[4] = {pq.x, pq.y, pq.z, pq.w};
    float t[4] = {tq.x, tq.y, tq.z, tq.w};

    // Conf of the cell that started in the previous lane ("cell A").
    float prov = (prov_idx == 0) ? t[0] : (prov_idx == 1) ? t[1]
               : (prov_idx == 2) ? t[2] : t[3];
    float t0a = __shfl_up(prov, 1);
    if (lane == 0 && r != 0) {
      t0a = targ[chunk * 256 - r];   // previous chunk's boundary conf
    }
    // Conf of the cell starting within this lane ("cell B"), if any.
    float tcs = (cstar == 0) ? t[0] : (cstar == 1) ? t[1]
              : (cstar == 2) ? t[2] : t[3];  // cstar==4 -> unused

#pragma unroll
    for (int c = 0; c < 4; ++c) {
      float d = t[c] - p[c];
      float d2 = d * d;
      if (c == cstar) {                 // conf element
        bool m = (t[c] == 1.0f);
        obj   += m ? d2 : 0.f;
        noobj += m ? 0.f : d2;
      } else {                          // coord element
        float t0 = (c < cstar) ? t0a : tcs;
        box += (t0 == 1.0f) ? d2 : 0.f;
      }
    }
  }

  // Generic tail (elements beyond full 256-chunks) — not hit for this size.
  {
    const long long tid = (long long)blockIdx.x * blockDim.x + threadIdx.x;
    const long long stride = (long long)gridDim.x * blockDim.x;
    for (long long e = nchunks * 256 + tid; e < nelem; e += stride) {
      long long comp = e % 5;
      float d = targ[e] - pred[e];
      float d2 = d * d;
      if (comp == 0) {
        bool m = (targ[e] == 1.0f);
        obj   += m ? d2 : 0.f;
        noobj += m ? 0.f : d2;
      } else {
        box += (targ[e - comp] == 1.0f) ? d2 : 0.f;
      }
    }
  }

  // Wave (64-lane) reduction.
#pragma unroll
  for (int off = 32; off > 0; off >>= 1) {
    box   += __shfl_down(box, off);
    obj   += __shfl_down(obj, off);
    noobj += __shfl_down(noobj, off);
  }

  __shared__ float s[3][4];
  const int wid = threadIdx.x >> 6;
  if (lane == 0) {
    s[0][wid] = box;
    s[1][wid] = obj;
    s[2][wid] = noobj;
  }
  __syncthreads();
  if (threadIdx.x == 0) {
    float b = s[0][0] + s[0][1] + s[0][2] + s[0][3];
    float o = s[1][0] + s[1][1] + s[1][2] + s[1][3];
    float n = s[2][0] + s[2][1] + s[2][2] + s[2][3];
    atomicAdd(&out[1], LAMBDA_COORD * b);
    atomicAdd(&out[2], o);
    atomicAdd(&out[3], LAMBDA_NOOBJ * n);
  }
}

__global__ void yolo_loss_finalize(float* __restrict__ out) {
  out[0] = out[1] + out[2] + out[3];
}

extern "C" void kernel_launch(void* const* d_in, const int* in_sizes, int n_in,
                              void* d_out, int out_size, void* d_ws, size_t ws_size,
                              hipStream_t stream) {
  const float* pred = (const float*)d_in[0];
  const float* targ = (const float*)d_in[1];
  float* out = (float*)d_out;

  const long long nelem = (long long)in_sizes[0];   // 32,768,000
  const long long nchunks = nelem / 256;            // 128,000

  // d_out is poisoned once and never re-zeroed between replays; the kernel
  // accumulates with atomics, so zero it ourselves every call.
  hipMemsetAsync(d_out, 0, out_size * sizeof(float), stream);

  // 1280 blocks = 5120 waves: divisible by 5 (phase invariance), 5 blocks/CU,
  // and 128,000 / 5120 = 25 exact iterations per wave.
  const int block = 256;
  const int grid = 1280;
  const int nwaves = (grid * block) / 64;
  yolo_loss_kernel<<<grid, block, 0, stream>>>(
      (const float4*)pred, (const float4*)targ, pred, targ, out,
      nchunks, nelem, nwaves);
  yolo_loss_finalize<<<1, 1, 0, stream>>>(out);
}